// Round 16
// baseline (486.755 us; speedup 1.0000x reference)
//
#include <hip/hip_runtime.h>
#include <hip/hip_bf16.h>

#define H_DIM 2048
#define I_DIM 768
#define NEXP 64
#define TOPK 8
#define NTOK 1024   // B*S
#define BM 256      // token tile (count ~128+-11 => single chunk)
#define BKS 32      // K per step

typedef float f32x4 __attribute__((ext_vector_type(4)));
typedef unsigned int u32x4 __attribute__((ext_vector_type(4)));
typedef unsigned int u32x2 __attribute__((ext_vector_type(2)));
typedef short bf16v8 __attribute__((ext_vector_type(8)));   // 8 bf16 in 4 VGPRs
typedef unsigned short u16x8 __attribute__((ext_vector_type(8)));
typedef unsigned int u32;

#define NTLOAD __builtin_nontemporal_load

// ---------------- workspace layout (bytes) ----------------
// topk_idx : int   [NTOK*TOPK]           @ 0
// topk_w   : float [NTOK*TOPK]           @ 32768
// counts   : int   [NEXP]                @ 65536
// offsets  : int   [NEXP]                @ 65792
// lists    : int   [NEXP*NTOK]           @ 66048    (ends 328192)
// wlist    : float [NEXP*NTOK]           @ 328192   (ends 590336)
// inv      : int   [NTOK*TOPK]           @ 590336   (ends 623104)
// hmid     : bf16  [NTOK*TOPK * I_DIM]   @ 623104   (ends 13206016)
// xbf      : bf16  [NTOK * H_DIM]        @ 13206016 (ends 17400320)
// part     : bf16  [NTOK*TOPK * H_DIM]   @ 17400320 (ends 50954752)
#define WS_NEEDED 50954752ull

__device__ inline unsigned short f2bf(float f) {
    union { float f; u32 u; } v; v.f = f;
    u32 r = (v.u + 0x7FFFu + ((v.u >> 16) & 1u)) >> 16;
    return (unsigned short)r;
}
__device__ inline u32 pack2(float a, float b) {
    return (u32)f2bf(a) | ((u32)f2bf(b) << 16);
}

// async 16B global -> LDS (wave-uniform LDS base + lane*16; per-lane global addr)
__device__ inline void async16(void* l, const void* g) {
    __builtin_amdgcn_global_load_lds(
        (const __attribute__((address_space(1))) unsigned int*)g,
        (__attribute__((address_space(3))) unsigned int*)l, 16, 0, 0);
}

__global__ void zero_kernel(float4* p, int n4) {
    int i = blockIdx.x * blockDim.x + threadIdx.x;
    if (i < n4) p[i] = (float4){0.f, 0.f, 0.f, 0.f};
}

// one block per token, 512 threads: fused x->bf16 conversion + 8-way-K router
__global__ __launch_bounds__(512) void router_kernel(
    const float* __restrict__ x, const float* __restrict__ Wr,
    int* __restrict__ topk_idx, float* __restrict__ topk_w,
    ushort4* __restrict__ xbf)
{
    const int t   = blockIdx.x;
    const int tid = threadIdx.x;
    const int lane = tid & 63;
    const int wv   = tid >> 6;           // 0..7 -> K chunk of 256
    __shared__ float xs[H_DIM];
    __shared__ float red[8][64];

    const float* xrow = x + (size_t)t * H_DIM;
    {
        const float4* src = (const float4*)xrow;
        float4 v = src[tid];
        ((float4*)xs)[tid] = v;
        ushort4 o;
        o.x = f2bf(v.x); o.y = f2bf(v.y); o.z = f2bf(v.z); o.w = f2bf(v.w);
        xbf[(size_t)t * (H_DIM / 4) + tid] = o;
    }
    __syncthreads();

    float acc = 0.f;
    const int h0 = wv * 256;
    #pragma unroll 8
    for (int h = h0; h < h0 + 256; ++h) acc += xs[h] * Wr[(size_t)h * NEXP + lane];
    red[wv][lane] = acc;
    __syncthreads();

    if (tid < 64) {
        const int e = tid;
        float logit = ((red[0][e] + red[1][e]) + (red[2][e] + red[3][e]))
                    + ((red[4][e] + red[5][e]) + (red[6][e] + red[7][e]));

        float m = logit;
        #pragma unroll
        for (int o = 32; o > 0; o >>= 1) m = fmaxf(m, __shfl_xor(m, o));
        float p = __expf(logit - m);
        float s = p;
        #pragma unroll
        for (int o = 32; o > 0; o >>= 1) s += __shfl_xor(s, o);
        float prob = p / s;

        float myp = prob;
        float kw[TOPK]; int kid[TOPK]; float wsum = 0.f;
        #pragma unroll
        for (int k = 0; k < TOPK; ++k) {
            float v = myp; int bi = e;
            #pragma unroll
            for (int o = 32; o > 0; o >>= 1) {
                float ov = __shfl_xor(v, o);
                int   oi = __shfl_xor(bi, o);
                if (ov > v || (ov == v && oi < bi)) { v = ov; bi = oi; }
            }
            kw[k] = v; kid[k] = bi; wsum += v;
            if (e == bi) myp = -1.f;
        }
        if (e == 0) {
            float inv = 1.f / wsum;
            #pragma unroll
            for (int k = 0; k < TOPK; ++k) {
                topk_idx[t * TOPK + k] = kid[k];
                topk_w[t * TOPK + k]   = kw[k] * inv;
            }
        }
    }
}

// one wave per expert; deterministic ordered compaction + inverse rank map
__global__ __launch_bounds__(64) void listbuild_kernel(
    const int* __restrict__ topk_idx, const float* __restrict__ topk_w,
    int* __restrict__ counts, int* __restrict__ lists, float* __restrict__ wlist,
    int* __restrict__ invmap)
{
    const int e = blockIdx.x;
    const int lane = threadIdx.x;
    int n = 0;
    for (int base = 0; base < NTOK * TOPK; base += 64) {
        int s = base + lane;
        int idx = topk_idx[s];
        bool match = (idx == e);
        unsigned long long mask = __ballot(match);
        int pre = __popcll(mask & ((1ull << lane) - 1ull));
        if (match) {
            lists[e * NTOK + n + pre] = s >> 3;
            wlist[e * NTOK + n + pre] = topk_w[s];
            invmap[s] = n + pre;
        }
        n += __popcll(mask);
    }
    if (lane == 0) counts[e] = n;
}

__global__ __launch_bounds__(64) void scan_kernel(
    const int* __restrict__ counts, int* __restrict__ offsets)
{
    int e = threadIdx.x;
    int v = counts[e];
    int xacc = v;
    #pragma unroll
    for (int o = 1; o < 64; o <<= 1) {
        int y = __shfl_up(xacc, o);
        if (e >= o) xacc += y;
    }
    offsets[e] = xacc - v;
}

#define MFMA_BF16 __builtin_amdgcn_mfma_f32_16x16x32_bf16
#define LGKM0()   asm volatile("s_waitcnt lgkmcnt(0)" ::: "memory")
#define RAWBAR()  __builtin_amdgcn_s_barrier()
#define VMCNT8()  asm volatile("s_waitcnt vmcnt(8)" ::: "memory")
#define VMCNT0()  asm volatile("s_waitcnt vmcnt(0)" ::: "memory")
#define FENCE()   asm volatile("" ::: "memory")

// ---------------- MFMA gate+up: grid 768 (xcd-swizzled), block 512, BN=64 ----------------
// A (xbf) via global_load_lds ring-2; B (both mats, 64 cols) reg-staged dbuf.
// BN=64 halves A re-reads (12 itiles): fabric bytes/output 3.0 -> 2.0
__global__ __launch_bounds__(512) void gateup_kernel(
    const unsigned short* __restrict__ xbf,
    const float* __restrict__ Wg, const float* __restrict__ Wu,
    const int* __restrict__ counts, const int* __restrict__ offsets,
    const int* __restrict__ lists, const float* __restrict__ wlist,
    unsigned short* __restrict__ hmid)
{
    const int b  = blockIdx.x;
    const int wg = (b & 7) * 96 + (b >> 3);      // bijective: 768 = 8*96
    const int itile = wg % 12;                   // 12 itiles of 64 cols
    const int e     = wg / 12;

    const int count = counts[e];
    if (count == 0) return;
    const int off = offsets[e];
    const int i0 = itile * 64;

    __shared__ unsigned short Alds[2][BM][32];   // 32768 B ring-2 (DMA dest)
    __shared__ u32 Bgl[2][64 * 20];              // 10240 B
    __shared__ u32 Bul[2][64 * 20];              // 10240 B

    const int tid  = threadIdx.x;
    const int lane = tid & 63;
    const int wid  = tid >> 6;
    const int wm   = wid >> 1, wn = wid & 1;
    const int kb   = lane >> 4;
    const int l15  = lane & 15;

    // B staging: tid -> (mat = tid>>8, col = tid&63, k-octet = (tid>>6)&3)
    const int bnn  = tid & 63;
    const int bkq  = (tid >> 6) & 3;
    const int bmat = tid >> 8;
    const float* WB = (bmat ? Wu : Wg) + (size_t)e * H_DIM * I_DIM + i0 + bnn;
    const int key4w = 4 * ((bnn >> 3) & 3);
    const int bwoff = bnn * 20 + ((4 * bkq) ^ key4w);
    // B fragment reads: two n-positions per wave
    const int brn0 = wn * 32 + l15;
    const int brn1 = wn * 32 + 16 + l15;
    const int key0 = 4 * ((brn0 >> 3) & 3);
    const int key1 = 4 * ((brn1 >> 3) & 3);

    // A DMA lane mapping (per wave 32 rows, 2 instrs): lane -> row,chunk
    const int c4  = lane & 3;
    const int r0  = wid * 32 + (lane >> 2);
    const int r1  = r0 + 16;
    const int awr0 = wid * 32;
    const int awr1 = wid * 32 + 16;
    // A fragment read offset (shorts): swizzled chunk = kb ^ ((l15>>1)&3)
    const int aoff = (wm * 64 + l15) * 32 + ((kb ^ ((l15 >> 1) & 3)) * 8);

    for (int mstart = 0; mstart < count; mstart += BM) {
        int p0 = mstart + r0; if (p0 >= count) p0 = count - 1;
        int p1 = mstart + r1; if (p1 >= count) p1 = count - 1;
        const unsigned short* srcA0 = xbf + (size_t)lists[e * NTOK + p0] * H_DIM
                                      + (size_t)((c4 ^ ((r0 >> 1) & 3)) * 8);
        const unsigned short* srcA1 = xbf + (size_t)lists[e * NTOK + p1] * H_DIM
                                      + (size_t)((c4 ^ ((r1 >> 1) & 3)) * 8);
        const bool mact = (mstart + wm * 64) < count;

        f32x4 accg[4][2], accu[4][2];
        #pragma unroll
        for (int i = 0; i < 4; ++i)
            #pragma unroll
            for (int j = 0; j < 2; ++j) {
                accg[i][j] = (f32x4){0.f, 0.f, 0.f, 0.f};
                accu[i][j] = (f32x4){0.f, 0.f, 0.f, 0.f};
            }

        float sA0, sA1, sA2, sA3, sA4, sA5, sA6, sA7;   // B prefetch set A
        float sB0, sB1, sB2, sB3, sB4, sB5, sB6, sB7;   // B prefetch set B

#define GU_LOADB(S0,S1,S2,S3,S4,S5,S6,S7,h)                                     \
        {                                                                       \
            const float* p_ = WB + (size_t)((h) + 8 * bkq) * I_DIM;             \
            S0 = NTLOAD(p_);             S1 = NTLOAD(p_ + I_DIM);               \
            S2 = NTLOAD(p_ + 2 * I_DIM); S3 = NTLOAD(p_ + 3 * I_DIM);           \
            S4 = NTLOAD(p_ + 4 * I_DIM); S5 = NTLOAD(p_ + 5 * I_DIM);           \
            S6 = NTLOAD(p_ + 6 * I_DIM); S7 = NTLOAD(p_ + 7 * I_DIM);           \
        }
#define GU_STOREB(BUF,S0,S1,S2,S3,S4,S5,S6,S7)                                  \
        {                                                                       \
            u32x4 w_;                                                           \
            w_.x = pack2(S0, S1); w_.y = pack2(S2, S3);                         \
            w_.z = pack2(S4, S5); w_.w = pack2(S6, S7);                         \
            *(u32x4*)((bmat ? Bul[BUF] : Bgl[BUF]) + bwoff) = w_;               \
        }
#define GU_DMAA(BUF,h)                                                          \
        {                                                                       \
            async16((void*)&Alds[BUF][awr0][0], (const void*)(srcA0 + (h)));    \
            async16((void*)&Alds[BUF][awr1][0], (const void*)(srcA1 + (h)));    \
        }
#define GU_MFMA(BUF)                                                            \
        if (mact) {                                                             \
            const unsigned short* Ab_ = (const unsigned short*)Alds[BUF];       \
            bf16v8 af[4];                                                       \
            _Pragma("unroll")                                                   \
            for (int mf = 0; mf < 4; ++mf)                                      \
                af[mf] = *(const bf16v8*)&Ab_[aoff + mf * 512];                 \
            bf16v8 bg0 = *(const bf16v8*)&Bgl[BUF][brn0 * 20 + ((4 * kb) ^ key0)]; \
            bf16v8 bg1 = *(const bf16v8*)&Bgl[BUF][brn1 * 20 + ((4 * kb) ^ key1)]; \
            bf16v8 bu0 = *(const bf16v8*)&Bul[BUF][brn0 * 20 + ((4 * kb) ^ key0)]; \
            bf16v8 bu1 = *(const bf16v8*)&Bul[BUF][brn1 * 20 + ((4 * kb) ^ key1)]; \
            _Pragma("unroll")                                                   \
            for (int mf = 0; mf < 4; ++mf) {                                    \
                accg[mf][0] = MFMA_BF16(af[mf], bg0, accg[mf][0], 0, 0, 0);     \
                accg[mf][1] = MFMA_BF16(af[mf], bg1, accg[mf][1], 0, 0, 0);     \
                accu[mf][0] = MFMA_BF16(af[mf], bu0, accu[mf][0], 0, 0, 0);     \
                accu[mf][1] = MFMA_BF16(af[mf], bu1, accu[mf][1], 0, 0, 0);     \
            }                                                                   \
        }
// phase t (PB = t&1): store B(t), issue B(t+2), vmcnt(8) keeps newest B-set
// (drains DMA@t-1 -> A slot t ready, B@t already forced by STOREB), barrier,
// issue A-DMA for t+1 into slot PB^1, MFMA(t)
#define GU_PHASE(PB,S0,S1,S2,S3,S4,S5,S6,S7,nhB,nhA,VM)                         \
        GU_STOREB(PB, S0, S1, S2, S3, S4, S5, S6, S7);                          \
        if ((nhB) < H_DIM) GU_LOADB(S0, S1, S2, S3, S4, S5, S6, S7, (nhB));     \
        VM();                                                                   \
        LGKM0();                                                                \
        RAWBAR();                                                               \
        FENCE();                                                                \
        if ((nhA) < H_DIM) GU_DMAA(PB ^ 1, (nhA));                              \
        FENCE();                                                                \
        __builtin_amdgcn_s_setprio(1);                                          \
        GU_MFMA(PB);                                                            \
        __builtin_amdgcn_s_setprio(0);

        // prologue: A slot0; B sets for phases 0,1
        GU_DMAA(0, 0);
        GU_LOADB(sA0, sA1, sA2, sA3, sA4, sA5, sA6, sA7, 0);
        GU_LOADB(sB0, sB1, sB2, sB3, sB4, sB5, sB6, sB7, BKS);

        for (int t2 = 0; t2 < 31; ++t2) {
            const int hh = t2 * 2 * BKS;
            GU_PHASE(0, sA0, sA1, sA2, sA3, sA4, sA5, sA6, sA7,
                     hh + 2 * BKS, hh + BKS,     VMCNT8);
            GU_PHASE(1, sB0, sB1, sB2, sB3, sB4, sB5, sB6, sB7,
                     hh + 3 * BKS, hh + 2 * BKS, VMCNT8);
        }
        // tail phases 62,63
        GU_PHASE(0, sA0, sA1, sA2, sA3, sA4, sA5, sA6, sA7,
                 H_DIM, 63 * BKS, VMCNT0);
        GU_PHASE(1, sB0, sB1, sB2, sB3, sB4, sB5, sB6, sB7,
                 H_DIM, H_DIM,    VMCNT0);
        __syncthreads();
#undef GU_LOADB
#undef GU_STOREB
#undef GU_DMAA
#undef GU_MFMA
#undef GU_PHASE

        if (mact) {
            #pragma unroll
            for (int mf = 0; mf < 4; ++mf)
                #pragma unroll
                for (int nf = 0; nf < 2; ++nf)
                    #pragma unroll
                    for (int r = 0; r < 4; ++r) {
                        int pos = mstart + wm * 64 + mf * 16 + kb * 4 + r;
                        if (pos < count) {
                            float wgt = wlist[e * NTOK + pos];
                            float g = accg[mf][nf][r], u = accu[mf][nf][r];
                            float s = 1.f / (1.f + __expf(-g));
                            hmid[(size_t)(off + pos) * I_DIM + i0 + wn * 32 + nf * 16 + l15]
                                = f2bf(g * s * u * wgt);
                        }
                    }
        }
    }
}

// ---------------- MFMA down: grid 2048 (xcd-swizzled), block 512, BN=64 ----------------
template <bool USE_PART>
__global__ __launch_bounds__(512) void down_kernel(
    const unsigned short* __restrict__ hmid, const float* __restrict__ Wd,
    const int* __restrict__ counts, const int* __restrict__ offsets,
    const int* __restrict__ lists, float* __restrict__ out,
    unsigned short* __restrict__ part)
{
    const int b  = blockIdx.x;
    const int wg = (b & 7) * 256 + (b >> 3);     // bijective: 2048 = 8*256
    const int htile = wg % 32;                   // 32 htiles of 64 cols
    const int e     = wg / 32;

    const int count = counts[e];
    if (count == 0) return;
    const int off = offsets[e];
    const int h0 = htile * 64;

    __shared__ unsigned short Alds[2][BM][32];   // 32768 B ring-2
    __shared__ u32 Bdl[2][64 * 20];              // 10240 B

    const int tid  = threadIdx.x;
    const int lane = tid & 63;
    const int wid  = tid >> 6;
    const int wm   = wid >> 1, wn = wid & 1;
    const int kb   = lane >> 4;
    const int l15  = lane & 15;

    // B staging: tid<256 -> (col = tid&63, k-octet = (tid>>6)&3)
    const int bnn  = tid & 63;
    const int bkq  = (tid >> 6) & 3;
    const bool bact = tid < 256;
    const float* WB = Wd + (size_t)e * I_DIM * H_DIM + h0 + bnn;
    const int key4w = 4 * ((bnn >> 3) & 3);
    const int bwoff = bnn * 20 + ((4 * bkq) ^ key4w);
    const int brn0 = wn * 32 + l15;
    const int brn1 = wn * 32 + 16 + l15;
    const int key0 = 4 * ((brn0 >> 3) & 3);
    const int key1 = 4 * ((brn1 >> 3) & 3);

    const int c4  = lane & 3;
    const int r0  = wid * 32 + (lane >> 2);
    const int r1  = r0 + 16;
    const int awr0 = wid * 32;
    const int awr1 = wid * 32 + 16;
    const int aoff = (wm * 64 + l15) * 32 + ((kb ^ ((l15 >> 1) & 3)) * 8);

    for (int mstart = 0; mstart < count; mstart += BM) {
        int p0 = mstart + r0; if (p0 >= count) p0 = count - 1;
        int p1 = mstart + r1; if (p1 >= count) p1 = count - 1;
        const unsigned short* srcA0 = hmid + (size_t)(off + p0) * I_DIM
                                      + (size_t)((c4 ^ ((r0 >> 1) & 3)) * 8);
        const unsigned short* srcA1 = hmid + (size_t)(off + p1) * I_DIM
                                      + (size_t)((c4 ^ ((r1 >> 1) & 3)) * 8);
        const bool mact = (mstart + wm * 64) < count;

        f32x4 acc[4][2];
        #pragma unroll
        for (int i = 0; i < 4; ++i)
            #pragma unroll
            for (int j = 0; j < 2; ++j) acc[i][j] = (f32x4){0.f, 0.f, 0.f, 0.f};

        float sA0, sA1, sA2, sA3, sA4, sA5, sA6, sA7;
        float sB0, sB1, sB2, sB3, sB4, sB5, sB6, sB7;

#define DN_LOADB(S0,S1,S2,S3,S4,S5,S6,S7,k)                                     \
        if (bact) {                                                             \
            const float* p_ = WB + (size_t)((k) + 8 * bkq) * H_DIM;             \
            S0 = NTLOAD(p_);             S1 = NTLOAD(p_ + H_DIM);               \
            S2 = NTLOAD(p_ + 2 * H_DIM); S3 = NTLOAD(p_ + 3 * H_DIM);           \
            S4 = NTLOAD(p_ + 4 * H_DIM); S5 = NTLOAD(p_ + 5 * H_DIM);           \
            S6 = NTLOAD(p_ + 6 * H_DIM); S7 = NTLOAD(p_ + 7 * H_DIM);           \
        }
#define DN_STOREB(BUF,S0,S1,S2,S3,S4,S5,S6,S7)                                  \
        if (bact) {                                                             \
            u32x4 w_;                                                           \
            w_.x = pack2(S0, S1); w_.y = pack2(S2, S3);                         \
            w_.z = pack2(S4, S5); w_.w = pack2(S6, S7);                         \
            *(u32x4*)(Bdl[BUF] + bwoff) = w_;                                   \
        }
#define DN_DMAA(BUF,k)                                                          \
        {                                                                       \
            async16((void*)&Alds[BUF][awr0][0], (const void*)(srcA0 + (k)));    \
            async16((void*)&Alds[BUF][awr1][0], (const void*)(srcA1 + (k)));    \
        }
#define DN_MFMA(BUF)                                                            \
        if (mact) {                                                             \
            const unsigned short* Ab_ = (const unsigned short*)Alds[BUF];       \
            bf16v8 af[4];                                                       \
            _Pragma("unroll")                                                   \
            for (int mf = 0; mf < 4; ++mf)                                      \
                af[mf] = *(const bf16v8*)&Ab_[aoff + mf * 512];                 \
            bf16v8 bd0 = *(const bf16v8*)&Bdl[BUF][brn0 * 20 + ((4 * kb) ^ key0)]; \
            bf16v8 bd1 = *(const bf16v8*)&Bdl[BUF][brn1 * 20 + ((4 * kb) ^ key1)]; \
            _Pragma("unroll")                                                   \
            for (int mf = 0; mf < 4; ++mf) {                                    \
                acc[mf][0] = MFMA_BF16(af[mf], bd0, acc[mf][0], 0, 0, 0);       \
                acc[mf][1] = MFMA_BF16(af[mf], bd1, acc[mf][1], 0, 0, 0);       \
            }                                                                   \
        }
#define DN_VMS()  { if (bact) { VMCNT8(); } else { VMCNT0(); } }
#define DN_PHASE(PB,S0,S1,S2,S3,S4,S5,S6,S7,nkB,nkA,VM)                         \
        DN_STOREB(PB, S0, S1, S2, S3, S4, S5, S6, S7);                          \
        if ((nkB) < I_DIM) DN_LOADB(S0, S1, S2, S3, S4, S5, S6, S7, (nkB));     \
        VM();                                                                   \
        LGKM0();                                                                \
        RAWBAR();                                                               \
        FENCE();                                                                \
        if ((nkA) < I_DIM) DN_DMAA(PB ^ 1, (nkA));                              \
        FENCE();                                                                \
        __builtin_amdgcn_s_setprio(1);                                          \
        DN_MFMA(PB);                                                            \
        __builtin_amdgcn_s_setprio(0);

        DN_DMAA(0, 0);
        DN_LOADB(sA0, sA1, sA2, sA3, sA4, sA5, sA6, sA7, 0);
        DN_LOADB(sB0, sB1, sB2, sB3, sB4, sB5, sB6, sB7, BKS);

        for (int t2 = 0; t2 < 11; ++t2) {
            const int ii = t2 * 2 * BKS;
            DN_PHASE(0, sA0, sA1, sA2, sA3, sA4, sA5, sA6, sA7,
                     ii + 2 * BKS, ii + BKS,     DN_VMS);
            DN_PHASE(1, sB0, sB1, sB2, sB3, sB4, sB5, sB6, sB7,
                     ii + 3 * BKS, ii + 2 * BKS, DN_VMS);
        }
        // tail phases 22,23
        DN_PHASE(0, sA0, sA1, sA2, sA3, sA4, sA5, sA6, sA7,
                 I_DIM, 23 * BKS, VMCNT0);
        DN_PHASE(1, sB0, sB1, sB2, sB3, sB4, sB5, sB6, sB7,
                 I_DIM, I_DIM,    VMCNT0);
        __syncthreads();
#undef DN_LOADB
#undef DN_STOREB
#undef DN_DMAA
#undef DN_MFMA
#undef DN_VMS
#undef DN_PHASE

        if (mact) {
            #pragma unroll
            for (int mf = 0; mf < 4; ++mf)
                #pragma unroll
                for (int nf = 0; nf < 2; ++nf)
                    #pragma unroll
                    for (int r = 0; r < 4; ++r) {
                        int pos = mstart + wm * 64 + mf * 16 + kb * 4 + r;
                        if (pos < count) {
                            if constexpr (USE_PART) {
                                part[(size_t)(off + pos) * H_DIM + h0 + wn * 32 + nf * 16 + l15]
                                    = f2bf(acc[mf][nf][r]);
                            } else {
                                int tok = lists[e * NTOK + pos];
                                atomicAdd(&out[(size_t)tok * H_DIM + h0 + wn * 32 + nf * 16 + l15],
                                          acc[mf][nf][r]);
                            }
                        }
                    }
        }
    }
}

// one block per token: sum its 8 partial rows (bf16) in fp32 -> out
__global__ __launch_bounds__(256) void reduce_kernel(
    const unsigned short* __restrict__ part,
    const int* __restrict__ topk_idx, const int* __restrict__ invmap,
    const int* __restrict__ offsets, float* __restrict__ out)
{
    const int t   = blockIdx.x;
    const int tid = threadIdx.x;
    __shared__ int slots[TOPK];
    if (tid < TOPK) {
        int s = t * TOPK + tid;
        slots[tid] = offsets[topk_idx[s]] + invmap[s];
    }
    __syncthreads();

    const int c = tid * 8;
    float acc[8] = {0.f, 0.f, 0.f, 0.f, 0.f, 0.f, 0.f, 0.f};
    #pragma unroll
    for (int k = 0; k < TOPK; ++k) {
        u16x8 v = *(const u16x8*)&part[(size_t)slots[k] * H_DIM + c];
        #pragma unroll
        for (int j = 0; j < 8; ++j)
            acc[j] += __uint_as_float((u32)(unsigned short)v[j] << 16);
    }
    float4* dst = (float4*)&out[(size_t)t * H_DIM + c];
    dst[0] = (float4){acc[0], acc[1], acc[2], acc[3]};
    dst[1] = (float4){acc[4], acc[5], acc[6], acc[7]};
}

extern "C" void kernel_launch(void* const* d_in, const int* in_sizes, int n_in,
                              void* d_out, int out_size, void* d_ws, size_t ws_size,
                              hipStream_t stream) {
    const float* x  = (const float*)d_in[0];
    const float* Wr = (const float*)d_in[1];
    const float* Wg = (const float*)d_in[2];
    const float* Wu = (const float*)d_in[3];
    const float* Wd = (const float*)d_in[4];
    float* out = (float*)d_out;

    char* ws = (char*)d_ws;
    int*   topk_idx = (int*)  (ws + 0);
    float* topk_w   = (float*)(ws + 32768);
    int*   counts   = (int*)  (ws + 65536);
    int*   offsets  = (int*)  (ws + 65792);
    int*   lists    = (int*)  (ws + 66048);
    float* wlist    = (float*)(ws + 328192);
    int*   invmap   = (int*)  (ws + 590336);
    unsigned short* hmid = (unsigned short*)(ws + 623104);
    unsigned short* xbf  = (unsigned short*)(ws + 13206016);
    unsigned short* part = (unsigned short*)(ws + 17400320);

    const bool usePart = ws_size >= WS_NEEDED;

    hipLaunchKernelGGL(router_kernel, dim3(NTOK), dim3(512), 0, stream,
                       x, Wr, topk_idx, topk_w, (ushort4*)xbf);
    hipLaunchKernelGGL(listbuild_kernel, dim3(NEXP), dim3(64), 0, stream,
                       topk_idx, topk_w, counts, lists, wlist, invmap);
    hipLaunchKernelGGL(scan_kernel, dim3(1), dim3(64), 0, stream,
                       counts, offsets);
    hipLaunchKernelGGL(gateup_kernel, dim3(12 * NEXP), dim3(512), 0, stream,
                       xbf, Wg, Wu, counts, offsets, lists, wlist, hmid);
    if (usePart) {
        hipLaunchKernelGGL((down_kernel<true>), dim3(32 * NEXP), dim3(512), 0, stream,
                           hmid, Wd, counts, offsets, lists, out, part);
        hipLaunchKernelGGL(reduce_kernel, dim3(NTOK), dim3(256), 0, stream,
                           part, topk_idx, invmap, offsets, out);
    } else {
        const int nout4 = NTOK * H_DIM / 4;
        hipLaunchKernelGGL(zero_kernel, dim3((nout4 + 255) / 256), dim3(256), 0, stream,
                           (float4*)out, nout4);
        hipLaunchKernelGGL((down_kernel<false>), dim3(32 * NEXP), dim3(512), 0, stream,
                           hmid, Wd, counts, offsets, lists, out, part);
    }
}

// Round 17
// 472.243 us; speedup vs baseline: 1.0307x; 1.0307x over previous
//
#include <hip/hip_runtime.h>
#include <hip/hip_bf16.h>

#define H_DIM 2048
#define I_DIM 768
#define NEXP 64
#define TOPK 8
#define NTOK 1024   // B*S
#define BM 256      // token tile (count ~128+-11 => single chunk)
#define BKS 32      // K per step

typedef float f32x4 __attribute__((ext_vector_type(4)));
typedef unsigned int u32x4 __attribute__((ext_vector_type(4)));
typedef unsigned int u32x2 __attribute__((ext_vector_type(2)));
typedef short bf16v8 __attribute__((ext_vector_type(8)));   // 8 bf16 in 4 VGPRs
typedef unsigned short u16x8 __attribute__((ext_vector_type(8)));
typedef unsigned int u32;

#define NTLOAD __builtin_nontemporal_load

// ---------------- workspace layout (bytes) ----------------
// topk_idx : int   [NTOK*TOPK]           @ 0
// topk_w   : float [NTOK*TOPK]           @ 32768
// counts   : int   [NEXP]                @ 65536
// offsets  : int   [NEXP]                @ 65792
// lists    : int   [NEXP*NTOK]           @ 66048    (ends 328192)
// wlist    : float [NEXP*NTOK]           @ 328192   (ends 590336)
// inv      : int   [NTOK*TOPK]           @ 590336   (ends 623104)
// hmid     : bf16  [NTOK*TOPK * I_DIM]   @ 623104   (ends 13206016)
// xbf      : bf16  [NTOK * H_DIM]        @ 13206016 (ends 17400320)
// part     : bf16  [NTOK*TOPK * H_DIM]   @ 17400320 (ends 50954752)
#define WS_NEEDED 50954752ull

__device__ inline unsigned short f2bf(float f) {
    union { float f; u32 u; } v; v.f = f;
    u32 r = (v.u + 0x7FFFu + ((v.u >> 16) & 1u)) >> 16;
    return (unsigned short)r;
}
__device__ inline u32 pack2(float a, float b) {
    return (u32)f2bf(a) | ((u32)f2bf(b) << 16);
}

__global__ void zero_kernel(float4* p, int n4) {
    int i = blockIdx.x * blockDim.x + threadIdx.x;
    if (i < n4) p[i] = (float4){0.f, 0.f, 0.f, 0.f};
}

// one block per token, 512 threads: fused x->bf16 conversion + 8-way-K router
__global__ __launch_bounds__(512) void router_kernel(
    const float* __restrict__ x, const float* __restrict__ Wr,
    int* __restrict__ topk_idx, float* __restrict__ topk_w,
    ushort4* __restrict__ xbf)
{
    const int t   = blockIdx.x;
    const int tid = threadIdx.x;
    const int lane = tid & 63;
    const int wv   = tid >> 6;           // 0..7 -> K chunk of 256
    __shared__ float xs[H_DIM];
    __shared__ float red[8][64];

    const float* xrow = x + (size_t)t * H_DIM;
    {
        const float4* src = (const float4*)xrow;
        float4 v = src[tid];             // 512 threads x float4 = 2048 floats
        ((float4*)xs)[tid] = v;
        ushort4 o;
        o.x = f2bf(v.x); o.y = f2bf(v.y); o.z = f2bf(v.z); o.w = f2bf(v.w);
        xbf[(size_t)t * (H_DIM / 4) + tid] = o;   // fused bf16 copy
    }
    __syncthreads();

    float acc = 0.f;
    const int h0 = wv * 256;
    #pragma unroll 8
    for (int h = h0; h < h0 + 256; ++h) acc += xs[h] * Wr[(size_t)h * NEXP + lane];
    red[wv][lane] = acc;
    __syncthreads();

    if (tid < 64) {
        const int e = tid;
        float logit = ((red[0][e] + red[1][e]) + (red[2][e] + red[3][e]))
                    + ((red[4][e] + red[5][e]) + (red[6][e] + red[7][e]));

        float m = logit;
        #pragma unroll
        for (int o = 32; o > 0; o >>= 1) m = fmaxf(m, __shfl_xor(m, o));
        float p = __expf(logit - m);
        float s = p;
        #pragma unroll
        for (int o = 32; o > 0; o >>= 1) s += __shfl_xor(s, o);
        float prob = p / s;

        float myp = prob;
        float kw[TOPK]; int kid[TOPK]; float wsum = 0.f;
        #pragma unroll
        for (int k = 0; k < TOPK; ++k) {
            float v = myp; int bi = e;
            #pragma unroll
            for (int o = 32; o > 0; o >>= 1) {
                float ov = __shfl_xor(v, o);
                int   oi = __shfl_xor(bi, o);
                if (ov > v || (ov == v && oi < bi)) { v = ov; bi = oi; }
            }
            kw[k] = v; kid[k] = bi; wsum += v;
            if (e == bi) myp = -1.f;
        }
        if (e == 0) {
            float inv = 1.f / wsum;
            #pragma unroll
            for (int k = 0; k < TOPK; ++k) {
                topk_idx[t * TOPK + k] = kid[k];
                topk_w[t * TOPK + k]   = kw[k] * inv;
            }
        }
    }
}

// one wave per expert; deterministic ordered compaction + inverse rank map
__global__ __launch_bounds__(64) void listbuild_kernel(
    const int* __restrict__ topk_idx, const float* __restrict__ topk_w,
    int* __restrict__ counts, int* __restrict__ lists, float* __restrict__ wlist,
    int* __restrict__ invmap)
{
    const int e = blockIdx.x;
    const int lane = threadIdx.x;
    int n = 0;
    for (int base = 0; base < NTOK * TOPK; base += 64) {
        int s = base + lane;
        int idx = topk_idx[s];
        bool match = (idx == e);
        unsigned long long mask = __ballot(match);
        int pre = __popcll(mask & ((1ull << lane) - 1ull));
        if (match) {
            lists[e * NTOK + n + pre] = s >> 3;
            wlist[e * NTOK + n + pre] = topk_w[s];
            invmap[s] = n + pre;
        }
        n += __popcll(mask);
    }
    if (lane == 0) counts[e] = n;
}

__global__ __launch_bounds__(64) void scan_kernel(
    const int* __restrict__ counts, int* __restrict__ offsets)
{
    int e = threadIdx.x;
    int v = counts[e];
    int xacc = v;
    #pragma unroll
    for (int o = 1; o < 64; o <<= 1) {
        int y = __shfl_up(xacc, o);
        if (e >= o) xacc += y;
    }
    offsets[e] = xacc - v;
}

#define MFMA_BF16 __builtin_amdgcn_mfma_f32_16x16x32_bf16
#define LGKM0()  asm volatile("s_waitcnt lgkmcnt(0)" ::: "memory")
#define RAWBAR() __builtin_amdgcn_s_barrier()

// ---------------- MFMA gate+up: grid 1536 (xcd-swizzled), block 512, BN=32 ----------------
// R11 core (best measured): LDS dbuf + raw barrier + counted vmcnt + setprio
__global__ __launch_bounds__(512) void gateup_kernel(
    const unsigned short* __restrict__ xbf,
    const float* __restrict__ Wg, const float* __restrict__ Wu,
    const int* __restrict__ counts, const int* __restrict__ offsets,
    const int* __restrict__ lists, const float* __restrict__ wlist,
    unsigned short* __restrict__ hmid)
{
    const int b  = blockIdx.x;
    const int wg = (b & 7) * 192 + (b >> 3);
    const int itile = wg % 24;
    const int e     = wg / 24;

    const int count = counts[e];
    if (count == 0) return;
    const int off = offsets[e];
    const int i0 = itile * 32;

    __shared__ unsigned short Alds[2][BM][40];   // 40960 B
    __shared__ u32 Bgl[2][32 * 20];              // 5120 B
    __shared__ u32 Bul[2][32 * 20];              // 5120 B

    const int tid  = threadIdx.x;
    const int lane = tid & 63;
    const int wid  = tid >> 6;
    const int wm   = wid >> 1, wn = wid & 1;
    const int kb   = lane >> 4;
    const int l15  = lane & 15;

    const int ar = tid >> 1;
    const int ah = (tid & 1) * 16;
    const int bnn  = tid & 31;
    const int bkq  = (tid >> 5) & 7;
    const int bmat = tid >> 8;
    const float* WB = (bmat ? Wu : Wg) + (size_t)e * H_DIM * I_DIM + i0 + bnn;
    const int key4w = 4 * ((bnn >> 3) & 3);
    const int bwoff = bnn * 20 + ((2 * bkq) ^ key4w);
    const int brn   = wn * 16 + l15;
    const int key4r = 4 * ((brn >> 3) & 3);

    for (int mstart = 0; mstart < count; mstart += BM) {
        const int pr = mstart + ar;
        const bool aact = pr < count;
        const unsigned short* xrow = xbf + (size_t)(aact ? lists[e * NTOK + pr] : 0) * H_DIM + ah;
        const bool mact = (mstart + wm * 64) < count;

        f32x4 accg[4], accu[4];
        #pragma unroll
        for (int i = 0; i < 4; ++i) {
            accg[i] = (f32x4){0.f, 0.f, 0.f, 0.f};
            accu[i] = (f32x4){0.f, 0.f, 0.f, 0.f};
        }

        u32x4 aA0, aA1, aB0, aB1;                 // A prefetch, 2 sets
        float bA0, bA1, bA2, bA3;                 // B prefetch set A
        float bB0, bB1, bB2, bB3;                 // B prefetch set B

#define GU_LOADA(P0,P1,h)                                                       \
        if (aact) {                                                             \
            const u32x4* pa_ = (const u32x4*)(xrow + (h));                      \
            P0 = pa_[0]; P1 = pa_[1];                                           \
        }
#define GU_LOADB(R0,R1,R2,R3,h)                                                 \
        {                                                                       \
            R0 = NTLOAD(WB + (size_t)((h) + 4 * bkq)     * I_DIM);              \
            R1 = NTLOAD(WB + (size_t)((h) + 4 * bkq + 1) * I_DIM);              \
            R2 = NTLOAD(WB + (size_t)((h) + 4 * bkq + 2) * I_DIM);              \
            R3 = NTLOAD(WB + (size_t)((h) + 4 * bkq + 3) * I_DIM);              \
        }
#define GU_STORE(BUF,P0,P1,R0,R1,R2,R3)                                         \
        if (aact) {                                                             \
            *(u32x4*)&Alds[BUF][ar][ah]     = P0;                               \
            *(u32x4*)&Alds[BUF][ar][ah + 8] = P1;                               \
        }                                                                       \
        {                                                                       \
            u32x2 w_; w_.x = pack2(R0, R1); w_.y = pack2(R2, R3);               \
            *(u32x2*)((bmat ? Bul[BUF] : Bgl[BUF]) + bwoff) = w_;               \
        }
#define GU_MFMA(BUF)                                                            \
        if (mact) {                                                             \
            bf16v8 af[4], bg, bu;                                               \
            _Pragma("unroll")                                                   \
            for (int mf = 0; mf < 4; ++mf)                                      \
                af[mf] = *(const bf16v8*)&Alds[BUF][wm * 64 + mf * 16 + l15][kb * 8]; \
            bg = *(const bf16v8*)&Bgl[BUF][brn * 20 + ((4 * kb) ^ key4r)];      \
            bu = *(const bf16v8*)&Bul[BUF][brn * 20 + ((4 * kb) ^ key4r)];      \
            _Pragma("unroll")                                                   \
            for (int mf = 0; mf < 4; ++mf) {                                    \
                accg[mf] = MFMA_BF16(af[mf], bg, accg[mf], 0, 0, 0);            \
                accu[mf] = MFMA_BF16(af[mf], bu, accu[mf], 0, 0, 0);            \
            }                                                                   \
        }
#define GU_PHASE(BUF,P0,P1,R0,R1,R2,R3,nh)                                      \
        GU_STORE(BUF, P0, P1, R0, R1, R2, R3);                                  \
        if ((nh) < H_DIM) { GU_LOADB(R0, R1, R2, R3, (nh)); GU_LOADA(P0, P1, (nh)); } \
        LGKM0();                                                                \
        RAWBAR();                                                               \
        __builtin_amdgcn_s_setprio(1);                                          \
        GU_MFMA(BUF);                                                           \
        __builtin_amdgcn_s_setprio(0);

        GU_LOADB(bA0, bA1, bA2, bA3, 0);    GU_LOADA(aA0, aA1, 0);
        GU_LOADB(bB0, bB1, bB2, bB3, BKS);  GU_LOADA(aB0, aB1, BKS);

        for (int hh = 0; hh < H_DIM; hh += 2 * BKS) {
            GU_PHASE(0, aA0, aA1, bA0, bA1, bA2, bA3, hh + 2 * BKS);
            GU_PHASE(1, aB0, aB1, bB0, bB1, bB2, bB3, hh + 3 * BKS);
        }
        __syncthreads();
#undef GU_LOADA
#undef GU_LOADB
#undef GU_STORE
#undef GU_MFMA
#undef GU_PHASE

        if (mact) {
            #pragma unroll
            for (int mf = 0; mf < 4; ++mf)
                #pragma unroll
                for (int r = 0; r < 4; ++r) {
                    int pos = mstart + wm * 64 + mf * 16 + kb * 4 + r;
                    if (pos < count) {
                        float wgt = wlist[e * NTOK + pos];
                        float g = accg[mf][r], u = accu[mf][r];
                        float s = 1.f / (1.f + __expf(-g));
                        hmid[(size_t)(off + pos) * I_DIM + i0 + wn * 16 + l15] = f2bf(g * s * u * wgt);
                    }
                }
        }
    }
}

// ---------------- MFMA down: grid 4096 (xcd-swizzled), block 512, BN=32 ----------------
template <bool USE_PART>
__global__ __launch_bounds__(512) void down_kernel(
    const unsigned short* __restrict__ hmid, const float* __restrict__ Wd,
    const int* __restrict__ counts, const int* __restrict__ offsets,
    const int* __restrict__ lists, float* __restrict__ out,
    unsigned short* __restrict__ part)
{
    const int b  = blockIdx.x;
    const int wg = (b & 7) * 512 + (b >> 3);
    const int htile = wg % 64;
    const int e     = wg / 64;

    const int count = counts[e];
    if (count == 0) return;
    const int off = offsets[e];
    const int h0 = htile * 32;

    __shared__ unsigned short Alds[2][BM][40];   // 40960 B
    __shared__ u32 Bdl[2][32 * 20];              // 5120 B

    const int tid  = threadIdx.x;
    const int lane = tid & 63;
    const int wid  = tid >> 6;
    const int wm   = wid >> 1, wn = wid & 1;
    const int kb   = lane >> 4;
    const int l15  = lane & 15;

    const int ar = tid >> 1;
    const int ah = (tid & 1) * 16;
    const int bnn  = tid & 31;
    const int bkq  = (tid >> 5) & 7;
    const bool bact = tid < 256;
    const float* WB = Wd + (size_t)e * I_DIM * H_DIM + h0 + bnn;
    const int key4w = 4 * ((bnn >> 3) & 3);
    const int bwoff = bnn * 20 + ((2 * bkq) ^ key4w);
    const int brn   = wn * 16 + l15;
    const int key4r = 4 * ((brn >> 3) & 3);

    for (int mstart = 0; mstart < count; mstart += BM) {
        const int pr = mstart + ar;
        const bool aact = pr < count;
        const unsigned short* hrow = hmid + (size_t)(off + (aact ? pr : 0)) * I_DIM + ah;
        const bool mact = (mstart + wm * 64) < count;

        f32x4 acc[4];
        #pragma unroll
        for (int i = 0; i < 4; ++i) acc[i] = (f32x4){0.f, 0.f, 0.f, 0.f};

        u32x4 aA0, aA1, aB0, aB1;
        float bA0, bA1, bA2, bA3;
        float bB0, bB1, bB2, bB3;

#define DN_LOADA(P0,P1,k)                                                       \
        if (aact) {                                                             \
            const u32x4* p_ = (const u32x4*)(hrow + (k));                       \
            P0 = p_[0]; P1 = p_[1];                                             \
        }
#define DN_LOADB(R0,R1,R2,R3,k)                                                 \
        if (bact) {                                                             \
            R0 = NTLOAD(WB + (size_t)((k) + 4 * bkq)     * H_DIM);              \
            R1 = NTLOAD(WB + (size_t)((k) + 4 * bkq + 1) * H_DIM);              \
            R2 = NTLOAD(WB + (size_t)((k) + 4 * bkq + 2) * H_DIM);              \
            R3 = NTLOAD(WB + (size_t)((k) + 4 * bkq + 3) * H_DIM);              \
        }
#define DN_STORE(BUF,P0,P1,R0,R1,R2,R3)                                         \
        if (aact) {                                                             \
            *(u32x4*)&Alds[BUF][ar][ah]     = P0;                               \
            *(u32x4*)&Alds[BUF][ar][ah + 8] = P1;                               \
        }                                                                       \
        if (bact) {                                                             \
            u32x2 w_; w_.x = pack2(R0, R1); w_.y = pack2(R2, R3);               \
            *(u32x2*)(Bdl[BUF] + bwoff) = w_;                                   \
        }
#define DN_MFMA(BUF)                                                            \
        if (mact) {                                                             \
            bf16v8 af[4], bd;                                                   \
            _Pragma("unroll")                                                   \
            for (int mf = 0; mf < 4; ++mf)                                      \
                af[mf] = *(const bf16v8*)&Alds[BUF][wm * 64 + mf * 16 + l15][kb * 8]; \
            bd = *(const bf16v8*)&Bdl[BUF][brn * 20 + ((4 * kb) ^ key4r)];      \
            _Pragma("unroll")                                                   \
            for (int mf = 0; mf < 4; ++mf)                                      \
                acc[mf] = MFMA_BF16(af[mf], bd, acc[mf], 0, 0, 0);              \
        }
#define DN_PHASE(BUF,P0,P1,R0,R1,R2,R3,nk)                                      \
        DN_STORE(BUF, P0, P1, R0, R1, R2, R3);                                  \
        if ((nk) < I_DIM) { DN_LOADB(R0, R1, R2, R3, (nk)); DN_LOADA(P0, P1, (nk)); } \
        LGKM0();                                                                \
        RAWBAR();                                                               \
        __builtin_amdgcn_s_setprio(1);                                          \
        DN_MFMA(BUF);                                                           \
        __builtin_amdgcn_s_setprio(0);

        DN_LOADB(bA0, bA1, bA2, bA3, 0);    DN_LOADA(aA0, aA1, 0);
        DN_LOADB(bB0, bB1, bB2, bB3, BKS);  DN_LOADA(aB0, aB1, BKS);

        for (int ii = 0; ii < I_DIM; ii += 2 * BKS) {
            DN_PHASE(0, aA0, aA1, bA0, bA1, bA2, bA3, ii + 2 * BKS);
            DN_PHASE(1, aB0, aB1, bB0, bB1, bB2, bB3, ii + 3 * BKS);
        }
        __syncthreads();
#undef DN_LOADA
#undef DN_LOADB
#undef DN_STORE
#undef DN_MFMA
#undef DN_PHASE

        if (mact) {
            #pragma unroll
            for (int mf = 0; mf < 4; ++mf)
                #pragma unroll
                for (int r = 0; r < 4; ++r) {
                    int pos = mstart + wm * 64 + mf * 16 + kb * 4 + r;
                    if (pos < count) {
                        if constexpr (USE_PART) {
                            part[(size_t)(off + pos) * H_DIM + h0 + wn * 16 + l15] =
                                f2bf(acc[mf][r]);
                        } else {
                            int tok = lists[e * NTOK + pos];
                            atomicAdd(&out[(size_t)tok * H_DIM + h0 + wn * 16 + l15],
                                      acc[mf][r]);
                        }
                    }
                }
        }
    }
}

// one block per token: sum its 8 partial rows (bf16) in fp32 -> out
__global__ __launch_bounds__(256) void reduce_kernel(
    const unsigned short* __restrict__ part,
    const int* __restrict__ topk_idx, const int* __restrict__ invmap,
    const int* __restrict__ offsets, float* __restrict__ out)
{
    const int t   = blockIdx.x;
    const int tid = threadIdx.x;
    __shared__ int slots[TOPK];
    if (tid < TOPK) {
        int s = t * TOPK + tid;
        slots[tid] = offsets[topk_idx[s]] + invmap[s];
    }
    __syncthreads();

    const int c = tid * 8;
    float acc[8] = {0.f, 0.f, 0.f, 0.f, 0.f, 0.f, 0.f, 0.f};
    #pragma unroll
    for (int k = 0; k < TOPK; ++k) {
        u16x8 v = *(const u16x8*)&part[(size_t)slots[k] * H_DIM + c];
        #pragma unroll
        for (int j = 0; j < 8; ++j)
            acc[j] += __uint_as_float((u32)(unsigned short)v[j] << 16);
    }
    float4* dst = (float4*)&out[(size_t)t * H_DIM + c];
    dst[0] = (float4){acc[0], acc[1], acc[2], acc[3]};
    dst[1] = (float4){acc[4], acc[5], acc[6], acc[7]};
}

extern "C" void kernel_launch(void* const* d_in, const int* in_sizes, int n_in,
                              void* d_out, int out_size, void* d_ws, size_t ws_size,
                              hipStream_t stream) {
    const float* x  = (const float*)d_in[0];
    const float* Wr = (const float*)d_in[1];
    const float* Wg = (const float*)d_in[2];
    const float* Wu = (const float*)d_in[3];
    const float* Wd = (const float*)d_in[4];
    float* out = (float*)d_out;

    char* ws = (char*)d_ws;
    int*   topk_idx = (int*)  (ws + 0);
    float* topk_w   = (float*)(ws + 32768);
    int*   counts   = (int*)  (ws + 65536);
    int*   offsets  = (int*)  (ws + 65792);
    int*   lists    = (int*)  (ws + 66048);
    float* wlist    = (float*)(ws + 328192);
    int*   invmap   = (int*)  (ws + 590336);
    unsigned short* hmid = (unsigned short*)(ws + 623104);
    unsigned short* xbf  = (unsigned short*)(ws + 13206016);
    unsigned short* part = (unsigned short*)(ws + 17400320);

    const bool usePart = ws_size >= WS_NEEDED;

    hipLaunchKernelGGL(router_kernel, dim3(NTOK), dim3(512), 0, stream,
                       x, Wr, topk_idx, topk_w, (ushort4*)xbf);
    hipLaunchKernelGGL(listbuild_kernel, dim3(NEXP), dim3(64), 0, stream,
                       topk_idx, topk_w, counts, lists, wlist, invmap);
    hipLaunchKernelGGL(scan_kernel, dim3(1), dim3(64), 0, stream,
                       counts, offsets);
    hipLaunchKernelGGL(gateup_kernel, dim3(24 * NEXP), dim3(512), 0, stream,
                       xbf, Wg, Wu, counts, offsets, lists, wlist, hmid);
    if (usePart) {
        hipLaunchKernelGGL((down_kernel<true>), dim3(64 * NEXP), dim3(512), 0, stream,
                           hmid, Wd, counts, offsets, lists, out, part);
        hipLaunchKernelGGL(reduce_kernel, dim3(NTOK), dim3(256), 0, stream,
                           part, topk_idx, invmap, offsets, out);
    } else {
        const int nout4 = NTOK * H_DIM / 4;
        hipLaunchKernelGGL(zero_kernel, dim3((nout4 + 255) / 256), dim3(256), 0, stream,
                           (float4*)out, nout4);
        hipLaunchKernelGGL((down_kernel<false>), dim3(64 * NEXP), dim3(512), 0, stream,
                           hmid, Wd, counts, offsets, lists, out, part);
    }
}

// Round 18
// 470.324 us; speedup vs baseline: 1.0349x; 1.0041x over previous
//
#include <hip/hip_runtime.h>
#include <hip/hip_bf16.h>

#define H_DIM 2048
#define I_DIM 768
#define NEXP 64
#define TOPK 8
#define NTOK 1024   // B*S
#define BM 256      // token tile (count ~128+-11 => single chunk)
#define BKS 32      // K per step

typedef float f32x4 __attribute__((ext_vector_type(4)));
typedef unsigned int u32x4 __attribute__((ext_vector_type(4)));
typedef unsigned int u32x2 __attribute__((ext_vector_type(2)));
typedef short bf16v8 __attribute__((ext_vector_type(8)));   // 8 bf16 in 4 VGPRs
typedef unsigned short u16x8 __attribute__((ext_vector_type(8)));
typedef unsigned int u32;

#define NTLOAD __builtin_nontemporal_load

// ---------------- workspace layout (bytes) ----------------
// topk_idx : int   [NTOK*TOPK]           @ 0
// topk_w   : float [NTOK*TOPK]           @ 32768
// counts   : int   [NEXP]                @ 65536
// offsets  : int   [NEXP]                @ 65792
// lists    : int   [NEXP*NTOK]           @ 66048    (ends 328192)
// wlist    : float [NEXP*NTOK]           @ 328192   (ends 590336)
// inv      : int   [NTOK*TOPK]           @ 590336   (ends 623104)
// hmid     : bf16  [NTOK*TOPK * I_DIM]   @ 623104   (ends 13206016)
// xbf      : bf16  [NTOK * H_DIM]        @ 13206016 (ends 17400320)
// part     : bf16  [NTOK*TOPK * H_DIM]   @ 17400320 (ends 50954752)
#define WS_NEEDED 50954752ull

__device__ inline unsigned short f2bf(float f) {
    union { float f; u32 u; } v; v.f = f;
    u32 r = (v.u + 0x7FFFu + ((v.u >> 16) & 1u)) >> 16;
    return (unsigned short)r;
}
__device__ inline u32 pack2(float a, float b) {
    return (u32)f2bf(a) | ((u32)f2bf(b) << 16);
}

__global__ void zero_kernel(float4* p, int n4) {
    int i = blockIdx.x * blockDim.x + threadIdx.x;
    if (i < n4) p[i] = (float4){0.f, 0.f, 0.f, 0.f};
}

// one block per token, 512 threads: fused x->bf16 conversion + 8-way-K router
__global__ __launch_bounds__(512) void router_kernel(
    const float* __restrict__ x, const float* __restrict__ Wr,
    int* __restrict__ topk_idx, float* __restrict__ topk_w,
    ushort4* __restrict__ xbf)
{
    const int t   = blockIdx.x;
    const int tid = threadIdx.x;
    const int lane = tid & 63;
    const int wv   = tid >> 6;           // 0..7 -> K chunk of 256
    __shared__ float xs[H_DIM];
    __shared__ float red[8][64];

    const float* xrow = x + (size_t)t * H_DIM;
    {
        const float4* src = (const float4*)xrow;
        float4 v = src[tid];             // 512 threads x float4 = 2048 floats
        ((float4*)xs)[tid] = v;
        ushort4 o;
        o.x = f2bf(v.x); o.y = f2bf(v.y); o.z = f2bf(v.z); o.w = f2bf(v.w);
        xbf[(size_t)t * (H_DIM / 4) + tid] = o;   // fused bf16 copy
    }
    __syncthreads();

    float acc = 0.f;
    const int h0 = wv * 256;
    #pragma unroll 8
    for (int h = h0; h < h0 + 256; ++h) acc += xs[h] * Wr[(size_t)h * NEXP + lane];
    red[wv][lane] = acc;
    __syncthreads();

    if (tid < 64) {
        const int e = tid;
        float logit = ((red[0][e] + red[1][e]) + (red[2][e] + red[3][e]))
                    + ((red[4][e] + red[5][e]) + (red[6][e] + red[7][e]));

        float m = logit;
        #pragma unroll
        for (int o = 32; o > 0; o >>= 1) m = fmaxf(m, __shfl_xor(m, o));
        float p = __expf(logit - m);
        float s = p;
        #pragma unroll
        for (int o = 32; o > 0; o >>= 1) s += __shfl_xor(s, o);
        float prob = p / s;

        float myp = prob;
        float kw[TOPK]; int kid[TOPK]; float wsum = 0.f;
        #pragma unroll
        for (int k = 0; k < TOPK; ++k) {
            float v = myp; int bi = e;
            #pragma unroll
            for (int o = 32; o > 0; o >>= 1) {
                float ov = __shfl_xor(v, o);
                int   oi = __shfl_xor(bi, o);
                if (ov > v || (ov == v && oi < bi)) { v = ov; bi = oi; }
            }
            kw[k] = v; kid[k] = bi; wsum += v;
            if (e == bi) myp = -1.f;
        }
        if (e == 0) {
            float inv = 1.f / wsum;
            #pragma unroll
            for (int k = 0; k < TOPK; ++k) {
                topk_idx[t * TOPK + k] = kid[k];
                topk_w[t * TOPK + k]   = kw[k] * inv;
            }
        }
    }
}

// one wave per expert; deterministic ordered compaction + inverse rank map
__global__ __launch_bounds__(64) void listbuild_kernel(
    const int* __restrict__ topk_idx, const float* __restrict__ topk_w,
    int* __restrict__ counts, int* __restrict__ lists, float* __restrict__ wlist,
    int* __restrict__ invmap)
{
    const int e = blockIdx.x;
    const int lane = threadIdx.x;
    int n = 0;
    for (int base = 0; base < NTOK * TOPK; base += 64) {
        int s = base + lane;
        int idx = topk_idx[s];
        bool match = (idx == e);
        unsigned long long mask = __ballot(match);
        int pre = __popcll(mask & ((1ull << lane) - 1ull));
        if (match) {
            lists[e * NTOK + n + pre] = s >> 3;
            wlist[e * NTOK + n + pre] = topk_w[s];
            invmap[s] = n + pre;
        }
        n += __popcll(mask);
    }
    if (lane == 0) counts[e] = n;
}

__global__ __launch_bounds__(64) void scan_kernel(
    const int* __restrict__ counts, int* __restrict__ offsets)
{
    int e = threadIdx.x;
    int v = counts[e];
    int xacc = v;
    #pragma unroll
    for (int o = 1; o < 64; o <<= 1) {
        int y = __shfl_up(xacc, o);
        if (e >= o) xacc += y;
    }
    offsets[e] = xacc - v;
}

#define MFMA_BF16 __builtin_amdgcn_mfma_f32_16x16x32_bf16
#define LGKM0()  asm volatile("s_waitcnt lgkmcnt(0)" ::: "memory")
#define RAWBAR() __builtin_amdgcn_s_barrier()

// ---------------- MFMA gate+up: grid 1536 (xcd-swizzled), block 512, BN=32 ----------------
// R13 core + __launch_bounds__(512,4): cap unified VGPR at 128 -> 2 blocks resident
__global__ __launch_bounds__(512, 4) void gateup_kernel(
    const unsigned short* __restrict__ xbf,
    const float* __restrict__ Wg, const float* __restrict__ Wu,
    const int* __restrict__ counts, const int* __restrict__ offsets,
    const int* __restrict__ lists, const float* __restrict__ wlist,
    unsigned short* __restrict__ hmid)
{
    const int b  = blockIdx.x;
    const int wg = (b & 7) * 192 + (b >> 3);
    const int itile = wg % 24;
    const int e     = wg / 24;

    const int count = counts[e];
    if (count == 0) return;
    const int off = offsets[e];
    const int i0 = itile * 32;

    __shared__ unsigned short Alds[2][BM][40];   // 40960 B
    __shared__ u32 Bgl[2][32 * 20];              // 5120 B
    __shared__ u32 Bul[2][32 * 20];              // 5120 B

    const int tid  = threadIdx.x;
    const int lane = tid & 63;
    const int wid  = tid >> 6;
    const int wm   = wid >> 1, wn = wid & 1;
    const int kb   = lane >> 4;
    const int l15  = lane & 15;

    const int ar = tid >> 1;
    const int ah = (tid & 1) * 16;
    const int bnn  = tid & 31;
    const int bkq  = (tid >> 5) & 7;
    const int bmat = tid >> 8;
    const float* WB = (bmat ? Wu : Wg) + (size_t)e * H_DIM * I_DIM + i0 + bnn;
    const int key4w = 4 * ((bnn >> 3) & 3);
    const int bwoff = bnn * 20 + ((2 * bkq) ^ key4w);
    const int brn   = wn * 16 + l15;
    const int key4r = 4 * ((brn >> 3) & 3);

    for (int mstart = 0; mstart < count; mstart += BM) {
        const int pr = mstart + ar;
        const bool aact = pr < count;
        const unsigned short* xrow = xbf + (size_t)(aact ? lists[e * NTOK + pr] : 0) * H_DIM + ah;
        const bool mact = (mstart + wm * 64) < count;

        f32x4 accg[4], accu[4];
        #pragma unroll
        for (int i = 0; i < 4; ++i) {
            accg[i] = (f32x4){0.f, 0.f, 0.f, 0.f};
            accu[i] = (f32x4){0.f, 0.f, 0.f, 0.f};
        }

        u32x4 aA0, aA1, aB0, aB1;                 // A prefetch, 2 sets
        float bA0, bA1, bA2, bA3;                 // B prefetch set A
        float bB0, bB1, bB2, bB3;                 // B prefetch set B

#define GU_LOADA(P0,P1,h)                                                       \
        if (aact) {                                                             \
            const u32x4* pa_ = (const u32x4*)(xrow + (h));                      \
            P0 = pa_[0]; P1 = pa_[1];                                           \
        }
#define GU_LOADB(R0,R1,R2,R3,h)                                                 \
        {                                                                       \
            R0 = NTLOAD(WB + (size_t)((h) + 4 * bkq)     * I_DIM);              \
            R1 = NTLOAD(WB + (size_t)((h) + 4 * bkq + 1) * I_DIM);              \
            R2 = NTLOAD(WB + (size_t)((h) + 4 * bkq + 2) * I_DIM);              \
            R3 = NTLOAD(WB + (size_t)((h) + 4 * bkq + 3) * I_DIM);              \
        }
#define GU_STORE(BUF,P0,P1,R0,R1,R2,R3)                                         \
        if (aact) {                                                             \
            *(u32x4*)&Alds[BUF][ar][ah]     = P0;                               \
            *(u32x4*)&Alds[BUF][ar][ah + 8] = P1;                               \
        }                                                                       \
        {                                                                       \
            u32x2 w_; w_.x = pack2(R0, R1); w_.y = pack2(R2, R3);               \
            *(u32x2*)((bmat ? Bul[BUF] : Bgl[BUF]) + bwoff) = w_;               \
        }
#define GU_MFMA(BUF)                                                            \
        if (mact) {                                                             \
            bf16v8 af[4], bg, bu;                                               \
            _Pragma("unroll")                                                   \
            for (int mf = 0; mf < 4; ++mf)                                      \
                af[mf] = *(const bf16v8*)&Alds[BUF][wm * 64 + mf * 16 + l15][kb * 8]; \
            bg = *(const bf16v8*)&Bgl[BUF][brn * 20 + ((4 * kb) ^ key4r)];      \
            bu = *(const bf16v8*)&Bul[BUF][brn * 20 + ((4 * kb) ^ key4r)];      \
            _Pragma("unroll")                                                   \
            for (int mf = 0; mf < 4; ++mf) {                                    \
                accg[mf] = MFMA_BF16(af[mf], bg, accg[mf], 0, 0, 0);            \
                accu[mf] = MFMA_BF16(af[mf], bu, accu[mf], 0, 0, 0);            \
            }                                                                   \
        }
#define GU_PHASE(BUF,P0,P1,R0,R1,R2,R3,nh)                                      \
        GU_STORE(BUF, P0, P1, R0, R1, R2, R3);                                  \
        if ((nh) < H_DIM) { GU_LOADB(R0, R1, R2, R3, (nh)); GU_LOADA(P0, P1, (nh)); } \
        LGKM0();                                                                \
        RAWBAR();                                                               \
        __builtin_amdgcn_s_setprio(1);                                          \
        GU_MFMA(BUF);                                                           \
        __builtin_amdgcn_s_setprio(0);

        GU_LOADB(bA0, bA1, bA2, bA3, 0);    GU_LOADA(aA0, aA1, 0);
        GU_LOADB(bB0, bB1, bB2, bB3, BKS);  GU_LOADA(aB0, aB1, BKS);

        for (int hh = 0; hh < H_DIM; hh += 2 * BKS) {
            GU_PHASE(0, aA0, aA1, bA0, bA1, bA2, bA3, hh + 2 * BKS);
            GU_PHASE(1, aB0, aB1, bB0, bB1, bB2, bB3, hh + 3 * BKS);
        }
        __syncthreads();
#undef GU_LOADA
#undef GU_LOADB
#undef GU_STORE
#undef GU_MFMA
#undef GU_PHASE

        if (mact) {
            #pragma unroll
            for (int mf = 0; mf < 4; ++mf)
                #pragma unroll
                for (int r = 0; r < 4; ++r) {
                    int pos = mstart + wm * 64 + mf * 16 + kb * 4 + r;
                    if (pos < count) {
                        float wgt = wlist[e * NTOK + pos];
                        float g = accg[mf][r], u = accu[mf][r];
                        float s = 1.f / (1.f + __expf(-g));
                        hmid[(size_t)(off + pos) * I_DIM + i0 + wn * 16 + l15] = f2bf(g * s * u * wgt);
                    }
                }
        }
    }
}

// ---------------- MFMA down: grid 4096 (xcd-swizzled), block 512, BN=32 ----------------
template <bool USE_PART>
__global__ __launch_bounds__(512, 4) void down_kernel(
    const unsigned short* __restrict__ hmid, const float* __restrict__ Wd,
    const int* __restrict__ counts, const int* __restrict__ offsets,
    const int* __restrict__ lists, float* __restrict__ out,
    unsigned short* __restrict__ part)
{
    const int b  = blockIdx.x;
    const int wg = (b & 7) * 512 + (b >> 3);
    const int htile = wg % 64;
    const int e     = wg / 64;

    const int count = counts[e];
    if (count == 0) return;
    const int off = offsets[e];
    const int h0 = htile * 32;

    __shared__ unsigned short Alds[2][BM][40];   // 40960 B
    __shared__ u32 Bdl[2][32 * 20];              // 5120 B

    const int tid  = threadIdx.x;
    const int lane = tid & 63;
    const int wid  = tid >> 6;
    const int wm   = wid >> 1, wn = wid & 1;
    const int kb   = lane >> 4;
    const int l15  = lane & 15;

    const int ar = tid >> 1;
    const int ah = (tid & 1) * 16;
    const int bnn  = tid & 31;
    const int bkq  = (tid >> 5) & 7;
    const bool bact = tid < 256;
    const float* WB = Wd + (size_t)e * I_DIM * H_DIM + h0 + bnn;
    const int key4w = 4 * ((bnn >> 3) & 3);
    const int bwoff = bnn * 20 + ((2 * bkq) ^ key4w);
    const int brn   = wn * 16 + l15;
    const int key4r = 4 * ((brn >> 3) & 3);

    for (int mstart = 0; mstart < count; mstart += BM) {
        const int pr = mstart + ar;
        const bool aact = pr < count;
        const unsigned short* hrow = hmid + (size_t)(off + (aact ? pr : 0)) * I_DIM + ah;
        const bool mact = (mstart + wm * 64) < count;

        f32x4 acc[4];
        #pragma unroll
        for (int i = 0; i < 4; ++i) acc[i] = (f32x4){0.f, 0.f, 0.f, 0.f};

        u32x4 aA0, aA1, aB0, aB1;
        float bA0, bA1, bA2, bA3;
        float bB0, bB1, bB2, bB3;

#define DN_LOADA(P0,P1,k)                                                       \
        if (aact) {                                                             \
            const u32x4* p_ = (const u32x4*)(hrow + (k));                       \
            P0 = p_[0]; P1 = p_[1];                                             \
        }
#define DN_LOADB(R0,R1,R2,R3,k)                                                 \
        if (bact) {                                                             \
            R0 = NTLOAD(WB + (size_t)((k) + 4 * bkq)     * H_DIM);              \
            R1 = NTLOAD(WB + (size_t)((k) + 4 * bkq + 1) * H_DIM);              \
            R2 = NTLOAD(WB + (size_t)((k) + 4 * bkq + 2) * H_DIM);              \
            R3 = NTLOAD(WB + (size_t)((k) + 4 * bkq + 3) * H_DIM);              \
        }
#define DN_STORE(BUF,P0,P1,R0,R1,R2,R3)                                         \
        if (aact) {                                                             \
            *(u32x4*)&Alds[BUF][ar][ah]     = P0;                               \
            *(u32x4*)&Alds[BUF][ar][ah + 8] = P1;                               \
        }                                                                       \
        if (bact) {                                                             \
            u32x2 w_; w_.x = pack2(R0, R1); w_.y = pack2(R2, R3);               \
            *(u32x2*)(Bdl[BUF] + bwoff) = w_;                                   \
        }
#define DN_MFMA(BUF)                                                            \
        if (mact) {                                                             \
            bf16v8 af[4], bd;                                                   \
            _Pragma("unroll")                                                   \
            for (int mf = 0; mf < 4; ++mf)                                      \
                af[mf] = *(const bf16v8*)&Alds[BUF][wm * 64 + mf * 16 + l15][kb * 8]; \
            bd = *(const bf16v8*)&Bdl[BUF][brn * 20 + ((4 * kb) ^ key4r)];      \
            _Pragma("unroll")                                                   \
            for (int mf = 0; mf < 4; ++mf)                                      \
                acc[mf] = MFMA_BF16(af[mf], bd, acc[mf], 0, 0, 0);              \
        }
#define DN_PHASE(BUF,P0,P1,R0,R1,R2,R3,nk)                                      \
        DN_STORE(BUF, P0, P1, R0, R1, R2, R3);                                  \
        if ((nk) < I_DIM) { DN_LOADB(R0, R1, R2, R3, (nk)); DN_LOADA(P0, P1, (nk)); } \
        LGKM0();                                                                \
        RAWBAR();                                                               \
        __builtin_amdgcn_s_setprio(1);                                          \
        DN_MFMA(BUF);                                                           \
        __builtin_amdgcn_s_setprio(0);

        DN_LOADB(bA0, bA1, bA2, bA3, 0);    DN_LOADA(aA0, aA1, 0);
        DN_LOADB(bB0, bB1, bB2, bB3, BKS);  DN_LOADA(aB0, aB1, BKS);

        for (int ii = 0; ii < I_DIM; ii += 2 * BKS) {
            DN_PHASE(0, aA0, aA1, bA0, bA1, bA2, bA3, ii + 2 * BKS);
            DN_PHASE(1, aB0, aB1, bB0, bB1, bB2, bB3, ii + 3 * BKS);
        }
        __syncthreads();
#undef DN_LOADA
#undef DN_LOADB
#undef DN_STORE
#undef DN_MFMA
#undef DN_PHASE

        if (mact) {
            #pragma unroll
            for (int mf = 0; mf < 4; ++mf)
                #pragma unroll
                for (int r = 0; r < 4; ++r) {
                    int pos = mstart + wm * 64 + mf * 16 + kb * 4 + r;
                    if (pos < count) {
                        if constexpr (USE_PART) {
                            part[(size_t)(off + pos) * H_DIM + h0 + wn * 16 + l15] =
                                f2bf(acc[mf][r]);
                        } else {
                            int tok = lists[e * NTOK + pos];
                            atomicAdd(&out[(size_t)tok * H_DIM + h0 + wn * 16 + l15],
                                      acc[mf][r]);
                        }
                    }
                }
        }
    }
}

// one block per token: sum its 8 partial rows (bf16) in fp32 -> out
__global__ __launch_bounds__(256) void reduce_kernel(
    const unsigned short* __restrict__ part,
    const int* __restrict__ topk_idx, const int* __restrict__ invmap,
    const int* __restrict__ offsets, float* __restrict__ out)
{
    const int t   = blockIdx.x;
    const int tid = threadIdx.x;
    __shared__ int slots[TOPK];
    if (tid < TOPK) {
        int s = t * TOPK + tid;
        slots[tid] = offsets[topk_idx[s]] + invmap[s];
    }
    __syncthreads();

    const int c = tid * 8;
    float acc[8] = {0.f, 0.f, 0.f, 0.f, 0.f, 0.f, 0.f, 0.f};
    #pragma unroll
    for (int k = 0; k < TOPK; ++k) {
        u16x8 v = *(const u16x8*)&part[(size_t)slots[k] * H_DIM + c];
        #pragma unroll
        for (int j = 0; j < 8; ++j)
            acc[j] += __uint_as_float((u32)(unsigned short)v[j] << 16);
    }
    float4* dst = (float4*)&out[(size_t)t * H_DIM + c];
    dst[0] = (float4){acc[0], acc[1], acc[2], acc[3]};
    dst[1] = (float4){acc[4], acc[5], acc[6], acc[7]};
}

extern "C" void kernel_launch(void* const* d_in, const int* in_sizes, int n_in,
                              void* d_out, int out_size, void* d_ws, size_t ws_size,
                              hipStream_t stream) {
    const float* x  = (const float*)d_in[0];
    const float* Wr = (const float*)d_in[1];
    const float* Wg = (const float*)d_in[2];
    const float* Wu = (const float*)d_in[3];
    const float* Wd = (const float*)d_in[4];
    float* out = (float*)d_out;

    char* ws = (char*)d_ws;
    int*   topk_idx = (int*)  (ws + 0);
    float* topk_w   = (float*)(ws + 32768);
    int*   counts   = (int*)  (ws + 65536);
    int*   offsets  = (int*)  (ws + 65792);
    int*   lists    = (int*)  (ws + 66048);
    float* wlist    = (float*)(ws + 328192);
    int*   invmap   = (int*)  (ws + 590336);
    unsigned short* hmid = (unsigned short*)(ws + 623104);
    unsigned short* xbf  = (unsigned short*)(ws + 13206016);
    unsigned short* part = (unsigned short*)(ws + 17400320);

    const bool usePart = ws_size >= WS_NEEDED;

    hipLaunchKernelGGL(router_kernel, dim3(NTOK), dim3(512), 0, stream,
                       x, Wr, topk_idx, topk_w, (ushort4*)xbf);
    hipLaunchKernelGGL(listbuild_kernel, dim3(NEXP), dim3(64), 0, stream,
                       topk_idx, topk_w, counts, lists, wlist, invmap);
    hipLaunchKernelGGL(scan_kernel, dim3(1), dim3(64), 0, stream,
                       counts, offsets);
    hipLaunchKernelGGL(gateup_kernel, dim3(24 * NEXP), dim3(512), 0, stream,
                       xbf, Wg, Wu, counts, offsets, lists, wlist, hmid);
    if (usePart) {
        hipLaunchKernelGGL((down_kernel<true>), dim3(64 * NEXP), dim3(512), 0, stream,
                           hmid, Wd, counts, offsets, lists, out, part);
        hipLaunchKernelGGL(reduce_kernel, dim3(NTOK), dim3(256), 0, stream,
                           part, topk_idx, invmap, offsets, out);
    } else {
        const int nout4 = NTOK * H_DIM / 4;
        hipLaunchKernelGGL(zero_kernel, dim3((nout4 + 255) / 256), dim3(256), 0, stream,
                           (float4*)out, nout4);
        hipLaunchKernelGGL((down_kernel<false>), dim3(64 * NEXP), dim3(512), 0, stream,
                           hmid, Wd, counts, offsets, lists, out, part);
    }
}